// Round 1
// baseline (537.168 us; speedup 1.0000x reference)
//
#include <hip/hip_runtime.h>

// Mixture-of-Experts, sparse top-2 implementation.
// Pipeline: router -> count/scan/scatter -> gather-GEMM1(bf16 MFMA, +bias,relu)
//           -> LN1 (in-place) -> grouped GEMM2 (+bias,relu) -> LN2 + gated combine.

#define E_N 8
#define TOPK 2
#define DM 1024
#define FF 4096
#define NTOK 4096           // B*S
#define NA 8192             // NTOK*TOPK assignments
#define LN_EPS 1e-5f

typedef __attribute__((ext_vector_type(4))) float f32x4;
typedef __attribute__((ext_vector_type(8))) short short8;

__device__ __forceinline__ unsigned short f2bf(float f) {
    unsigned int u = __builtin_bit_cast(unsigned int, f);
    u = (u + 0x7FFFu + ((u >> 16) & 1u)) >> 16;   // RNE
    return (unsigned short)u;
}
__device__ __forceinline__ float bf2f(unsigned short h) {
    unsigned int u = ((unsigned int)h) << 16;
    return __builtin_bit_cast(float, u);
}
__device__ __forceinline__ void unp(unsigned int u, float& lo, float& hi) {
    lo = bf2f((unsigned short)(u & 0xffffu));
    hi = bf2f((unsigned short)(u >> 16));
}
__device__ __forceinline__ unsigned int pk(float lo, float hi) {
    return (unsigned int)f2bf(lo) | ((unsigned int)f2bf(hi) << 16);
}

// ---------------- small utility kernels ----------------

__global__ void k_zero(int* p) { p[threadIdx.x] = 0; }

__global__ void k_conv_bf16(const float* __restrict__ src, unsigned short* __restrict__ dst, int n4) {
    int i = blockIdx.x * blockDim.x + threadIdx.x;
    if (i >= n4) return;
    float4 v = ((const float4*)src)[i];
    unsigned long long r =
        (unsigned long long)pk(v.x, v.y) | ((unsigned long long)pk(v.z, v.w) << 32);
    ((unsigned long long*)dst)[i] = r;
}

// [E][R][C] f32 -> [E][C][R] bf16  (tiled 32x32)
__global__ void k_transpose_bf16(const float* __restrict__ src, unsigned short* __restrict__ dst,
                                 int R, int C) {
    __shared__ float tile[32][33];
    size_t e = blockIdx.z;
    const float* s = src + e * (size_t)R * C;
    unsigned short* d = dst + e * (size_t)R * C;
    int c0 = blockIdx.x * 32, r0 = blockIdx.y * 32;
    int tx = threadIdx.x, ty = threadIdx.y;
#pragma unroll
    for (int i = 0; i < 4; i++)
        tile[ty + i * 8][tx] = s[(size_t)(r0 + ty + i * 8) * C + (c0 + tx)];
    __syncthreads();
#pragma unroll
    for (int i = 0; i < 4; i++)
        d[(size_t)(c0 + ty + i * 8) * R + (r0 + tx)] = f2bf(tile[tx][ty + i * 8]);
}

// ---------------- router: logits -> softmax -> top2 -> renorm ----------------

__global__ __launch_bounds__(256) void k_router(const float* __restrict__ x,
        const float* __restrict__ Wr, const float* __restrict__ br,
        int* __restrict__ topk_idx, float* __restrict__ topk_p, int* __restrict__ cnt)
{
    int wv = threadIdx.x >> 6, lane = threadIdx.x & 63;
    int t = blockIdx.x * 4 + wv;
    const float* xr = x + (size_t)t * DM;
    float a0=0,a1=0,a2=0,a3=0,a4=0,a5=0,a6=0,a7=0;
    for (int d = lane; d < DM; d += 64) {
        float xv = xr[d];
        const float4* wp = (const float4*)(Wr + d * 8);
        float4 w0 = wp[0], w1 = wp[1];
        a0 += xv * w0.x; a1 += xv * w0.y; a2 += xv * w0.z; a3 += xv * w0.w;
        a4 += xv * w1.x; a5 += xv * w1.y; a6 += xv * w1.z; a7 += xv * w1.w;
    }
#pragma unroll
    for (int off = 32; off; off >>= 1) {
        a0 += __shfl_xor(a0, off); a1 += __shfl_xor(a1, off);
        a2 += __shfl_xor(a2, off); a3 += __shfl_xor(a3, off);
        a4 += __shfl_xor(a4, off); a5 += __shfl_xor(a5, off);
        a6 += __shfl_xor(a6, off); a7 += __shfl_xor(a7, off);
    }
    if (lane == 0) {
        float l[8] = {a0 + br[0], a1 + br[1], a2 + br[2], a3 + br[3],
                      a4 + br[4], a5 + br[5], a6 + br[6], a7 + br[7]};
        int i0 = 0;
#pragma unroll
        for (int e = 1; e < 8; e++) if (l[e] > l[i0]) i0 = e;
        int i1 = (i0 == 0) ? 1 : 0;
#pragma unroll
        for (int e = 0; e < 8; e++) if (e != i0 && l[e] > l[i1]) i1 = e;
        // renormalized top-2 probs == softmax over the two logits
        float p1 = expf(l[i1] - l[i0]);
        float s = 1.0f + p1;
        topk_idx[2 * t]     = i0;
        topk_idx[2 * t + 1] = i1;
        topk_p[2 * t]       = 1.0f / s;
        topk_p[2 * t + 1]   = p1 / s;
        atomicAdd(&cnt[i0], 1);
        atomicAdd(&cnt[i1], 1);
    }
}

__global__ void k_scan(const int* __restrict__ cnt, int* __restrict__ offs, int* __restrict__ fill) {
    if (threadIdx.x == 0) {
        int s = 0;
        for (int e = 0; e < E_N; e++) { offs[e] = s; fill[e] = s; s += cnt[e]; }
        offs[E_N] = s;
    }
}

__global__ void k_scatter(const int* __restrict__ topk_idx, int* __restrict__ fill,
                          int* __restrict__ assign_tok, int* __restrict__ assign_e,
                          int* __restrict__ slot) {
    int t = blockIdx.x * blockDim.x + threadIdx.x;
    if (t >= NTOK) return;
#pragma unroll
    for (int k = 0; k < TOPK; k++) {
        int e = topk_idx[2 * t + k];
        int pos = atomicAdd(&fill[e], 1);
        assign_tok[pos] = t;
        assign_e[pos] = e;
        slot[2 * t + k] = pos;
    }
}

// ---------------- grouped/gather GEMM (bf16 MFMA 16x16x32) ----------------
// C[off_e+m][n] = relu( sum_k A[row(m)][k] * BT[e][n][k] + bias[e][n] ), m < cnt[e]

#define BM 128
#define BN 128
#define BKK 64
#define LDP 72   // 64 + 8 pad (bf16 elems): stride 144B -> frag reads ~conflict-free

__global__ __launch_bounds__(256) void k_gemm(
    const unsigned short* __restrict__ A,
    const unsigned short* __restrict__ BT,
    const float* __restrict__ bias,
    unsigned short* __restrict__ C,
    const int* __restrict__ cnt, const int* __restrict__ offs,
    const int* __restrict__ gather_tok,
    int K, int N, int ldA)
{
    __shared__ __align__(16) unsigned short A_lds[BM][LDP];
    __shared__ __align__(16) unsigned short B_lds[BN][LDP];
    int e = blockIdx.z;
    int M = cnt[e];
    int m0 = blockIdx.y * BM;
    if (m0 >= M) return;
    int n0 = blockIdx.x * BN;
    int off_e = offs[e];
    int tid = threadIdx.x;

    // staging: 2 threads per row, 4x b128 chunks each
    int sr = tid >> 1;
    int sc = (tid & 1) * 32;
    int mrow = m0 + sr; mrow = (mrow < M) ? mrow : (M - 1);
    size_t arowi = gather_tok ? (size_t)gather_tok[off_e + mrow] : (size_t)(off_e + mrow);
    const unsigned short* aptr = A + arowi * (size_t)ldA + sc;
    const unsigned short* bptr = BT + ((size_t)e * N + (n0 + sr)) * (size_t)K + sc;

    int wv = tid >> 6, lane = tid & 63;
    int mW = (wv >> 1) * 64, nW = (wv & 1) * 64;
    int lr = lane & 15, kg = (lane >> 4) * 8;

    f32x4 acc[4][4];
    f32x4 zz = {0.f, 0.f, 0.f, 0.f};
#pragma unroll
    for (int mi = 0; mi < 4; mi++)
#pragma unroll
        for (int ni = 0; ni < 4; ni++) acc[mi][ni] = zz;

    for (int k0 = 0; k0 < K; k0 += BKK) {
        __syncthreads();
#pragma unroll
        for (int i = 0; i < 4; i++) {
            *(uint4*)&A_lds[sr][sc + i * 8] = *(const uint4*)(aptr + k0 + i * 8);
            *(uint4*)&B_lds[sr][sc + i * 8] = *(const uint4*)(bptr + k0 + i * 8);
        }
        __syncthreads();
#pragma unroll
        for (int ks = 0; ks < 2; ks++) {
            short8 af[4], bf[4];
#pragma unroll
            for (int mi = 0; mi < 4; mi++)
                af[mi] = *(const short8*)&A_lds[mW + mi * 16 + lr][ks * 32 + kg];
#pragma unroll
            for (int ni = 0; ni < 4; ni++)
                bf[ni] = *(const short8*)&B_lds[nW + ni * 16 + lr][ks * 32 + kg];
#pragma unroll
            for (int mi = 0; mi < 4; mi++)
#pragma unroll
                for (int ni = 0; ni < 4; ni++)
                    acc[mi][ni] = __builtin_amdgcn_mfma_f32_16x16x32_bf16(
                        af[mi], bf[ni], acc[mi][ni], 0, 0, 0);
        }
    }

    int lq = lane >> 4;
    float bv[4];
#pragma unroll
    for (int ni = 0; ni < 4; ni++)
        bv[ni] = bias[(size_t)e * N + (n0 + nW + ni * 16 + lr)];
#pragma unroll
    for (int mi = 0; mi < 4; mi++) {
        int mb = m0 + mW + mi * 16 + lq * 4;
#pragma unroll
        for (int r = 0; r < 4; r++) {
            int m = mb + r;
            if (m < M) {
                unsigned short* crow = C + (size_t)(off_e + m) * N;
#pragma unroll
                for (int ni = 0; ni < 4; ni++) {
                    float v = fmaxf(acc[mi][ni][r] + bv[ni], 0.0f);
                    crow[n0 + nW + ni * 16 + lr] = f2bf(v);
                }
            }
        }
    }
}

// ---------------- LN1 over F, in-place on h ----------------

__global__ __launch_bounds__(256) void k_ln1(unsigned short* __restrict__ H,
        const float* __restrict__ g, const float* __restrict__ b,
        const int* __restrict__ assign_e)
{
    size_t a = blockIdx.x;
    int e = assign_e[a];
    unsigned short* row = H + a * FF;
    int tid = threadIdx.x;
    uint4 u0 = *(const uint4*)(row + tid * 16);
    uint4 u1 = *(const uint4*)(row + tid * 16 + 8);
    float v[16];
    unp(u0.x, v[0], v[1]);  unp(u0.y, v[2], v[3]);
    unp(u0.z, v[4], v[5]);  unp(u0.w, v[6], v[7]);
    unp(u1.x, v[8], v[9]);  unp(u1.y, v[10], v[11]);
    unp(u1.z, v[12], v[13]); unp(u1.w, v[14], v[15]);
    float s = 0.f, q = 0.f;
#pragma unroll
    for (int i = 0; i < 16; i++) { s += v[i]; q += v[i] * v[i]; }
#pragma unroll
    for (int off = 32; off; off >>= 1) { s += __shfl_xor(s, off); q += __shfl_xor(q, off); }
    __shared__ float red[8];
    int wv = tid >> 6, lane = tid & 63;
    if (lane == 0) { red[wv * 2] = s; red[wv * 2 + 1] = q; }
    __syncthreads();
    s = red[0] + red[2] + red[4] + red[6];
    q = red[1] + red[3] + red[5] + red[7];
    float mu = s * (1.0f / FF);
    float var = q * (1.0f / FF) - mu * mu;
    float rstd = rsqrtf(var + LN_EPS);
    const float* gg = g + (size_t)e * FF + tid * 16;
    const float* bb = b + (size_t)e * FF + tid * 16;
    float4 G0 = *(const float4*)(gg);      float4 G1 = *(const float4*)(gg + 4);
    float4 G2 = *(const float4*)(gg + 8);  float4 G3 = *(const float4*)(gg + 12);
    float4 B0 = *(const float4*)(bb);      float4 B1 = *(const float4*)(bb + 4);
    float4 B2 = *(const float4*)(bb + 8);  float4 B3 = *(const float4*)(bb + 12);
    float gvv[16] = {G0.x,G0.y,G0.z,G0.w,G1.x,G1.y,G1.z,G1.w,G2.x,G2.y,G2.z,G2.w,G3.x,G3.y,G3.z,G3.w};
    float bvv[16] = {B0.x,B0.y,B0.z,B0.w,B1.x,B1.y,B1.z,B1.w,B2.x,B2.y,B2.z,B2.w,B3.x,B3.y,B3.z,B3.w};
#pragma unroll
    for (int i = 0; i < 16; i++) v[i] = (v[i] - mu) * rstd * gvv[i] + bvv[i];
    u0.x = pk(v[0], v[1]);  u0.y = pk(v[2], v[3]);
    u0.z = pk(v[4], v[5]);  u0.w = pk(v[6], v[7]);
    u1.x = pk(v[8], v[9]);  u1.y = pk(v[10], v[11]);
    u1.z = pk(v[12], v[13]); u1.w = pk(v[14], v[15]);
    *(uint4*)(row + tid * 16) = u0;
    *(uint4*)(row + tid * 16 + 8) = u1;
}

// ---------------- LN2 + gated combine ----------------

__global__ __launch_bounds__(256) void k_comb(const unsigned short* __restrict__ Y,
        const float* __restrict__ g, const float* __restrict__ b,
        const int* __restrict__ slot, const float* __restrict__ topk_p,
        const int* __restrict__ assign_e, float* __restrict__ out)
{
    int t = blockIdx.x;
    int s0 = slot[2 * t], s1 = slot[2 * t + 1];
    float p0 = topk_p[2 * t], p1 = topk_p[2 * t + 1];
    int e0 = assign_e[s0], e1 = assign_e[s1];
    int tid = threadIdx.x;
    uint2 ua = *(const uint2*)(Y + (size_t)s0 * DM + tid * 4);
    uint2 ub = *(const uint2*)(Y + (size_t)s1 * DM + tid * 4);
    float va[4], vb[4];
    unp(ua.x, va[0], va[1]); unp(ua.y, va[2], va[3]);
    unp(ub.x, vb[0], vb[1]); unp(ub.y, vb[2], vb[3]);
    float sa = 0.f, qa = 0.f, sb = 0.f, qb = 0.f;
#pragma unroll
    for (int i = 0; i < 4; i++) {
        sa += va[i]; qa += va[i] * va[i];
        sb += vb[i]; qb += vb[i] * vb[i];
    }
#pragma unroll
    for (int off = 32; off; off >>= 1) {
        sa += __shfl_xor(sa, off); qa += __shfl_xor(qa, off);
        sb += __shfl_xor(sb, off); qb += __shfl_xor(qb, off);
    }
    __shared__ float red[16];
    int wv = tid >> 6, lane = tid & 63;
    if (lane == 0) { red[wv*4+0]=sa; red[wv*4+1]=qa; red[wv*4+2]=sb; red[wv*4+3]=qb; }
    __syncthreads();
    sa = red[0] + red[4] + red[8]  + red[12];
    qa = red[1] + red[5] + red[9]  + red[13];
    sb = red[2] + red[6] + red[10] + red[14];
    qb = red[3] + red[7] + red[11] + red[15];
    float mua = sa * (1.0f / DM), vara = qa * (1.0f / DM) - mua * mua;
    float ra = rsqrtf(vara + LN_EPS);
    float mub = sb * (1.0f / DM), varb = qb * (1.0f / DM) - mub * mub;
    float rb = rsqrtf(varb + LN_EPS);
    int d = tid * 4;
    float4 ga  = *(const float4*)(g + (size_t)e0 * DM + d);
    float4 ba  = *(const float4*)(b + (size_t)e0 * DM + d);
    float4 gb4 = *(const float4*)(g + (size_t)e1 * DM + d);
    float4 bb4 = *(const float4*)(b + (size_t)e1 * DM + d);
    float4 o;
    o.x = p0 * ((va[0] - mua) * ra * ga.x + ba.x) + p1 * ((vb[0] - mub) * rb * gb4.x + bb4.x);
    o.y = p0 * ((va[1] - mua) * ra * ga.y + ba.y) + p1 * ((vb[1] - mub) * rb * gb4.y + bb4.y);
    o.z = p0 * ((va[2] - mua) * ra * ga.z + ba.z) + p1 * ((vb[2] - mub) * rb * gb4.z + bb4.z);
    o.w = p0 * ((va[3] - mua) * ra * ga.w + ba.w) + p1 * ((vb[3] - mub) * rb * gb4.w + bb4.w);
    *(float4*)(out + (size_t)t * DM + d) = o;
}

// ---------------- launch ----------------

extern "C" void kernel_launch(void* const* d_in, const int* in_sizes, int n_in,
                              void* d_out, int out_size, void* d_ws, size_t ws_size,
                              hipStream_t stream) {
    const float* x   = (const float*)d_in[0];
    const float* Wr  = (const float*)d_in[1];
    const float* br  = (const float*)d_in[2];
    const float* W1  = (const float*)d_in[3];
    const float* b1  = (const float*)d_in[4];
    const float* g1  = (const float*)d_in[5];
    const float* be1 = (const float*)d_in[6];
    const float* W2  = (const float*)d_in[7];
    const float* b2  = (const float*)d_in[8];
    const float* g2  = (const float*)d_in[9];
    const float* be2 = (const float*)d_in[10];
    float* out = (float*)d_out;

    char* w = (char*)d_ws;
    int*   cnt        = (int*)(w);
    int*   fill       = (int*)(w + 64);
    int*   offs       = (int*)(w + 128);
    int*   topk_idx   = (int*)(w + 512);
    float* topk_p     = (float*)(w + 512 + (32 << 10));
    int*   assign_tok = (int*)(w + 512 + (64 << 10));
    int*   assign_e   = (int*)(w + 512 + (96 << 10));
    int*   slot       = (int*)(w + 512 + (128 << 10));
    unsigned short* xb  = (unsigned short*)(w + ((size_t)1 << 20));
    unsigned short* W1T = (unsigned short*)(w + ((size_t)9 << 20));    // [E][F][D] bf16, 64MB
    unsigned short* W2T = (unsigned short*)(w + ((size_t)73 << 20));   // [E][D][F] bf16, 64MB
    unsigned short* Hb  = (unsigned short*)(w + ((size_t)137 << 20));  // [NA][F] bf16, 64MB
    unsigned short* Yb  = (unsigned short*)(w + ((size_t)201 << 20));  // [NA][D] bf16, 16MB
    // total ws use: 217 MB

    k_zero<<<1, 64, 0, stream>>>((int*)w);
    k_conv_bf16<<<(NTOK * DM / 4 + 255) / 256, 256, 0, stream>>>(x, xb, NTOK * DM / 4);
    dim3 tb(32, 8);
    k_transpose_bf16<<<dim3(FF / 32, DM / 32, E_N), tb, 0, stream>>>(W1, W1T, DM, FF);
    k_transpose_bf16<<<dim3(DM / 32, FF / 32, E_N), tb, 0, stream>>>(W2, W2T, FF, DM);
    k_router<<<NTOK / 4, 256, 0, stream>>>(x, Wr, br, topk_idx, topk_p, cnt);
    k_scan<<<1, 64, 0, stream>>>(cnt, offs, fill);
    k_scatter<<<NTOK / 256, 256, 0, stream>>>(topk_idx, fill, assign_tok, assign_e, slot);
    // GEMM1: A = gathered x_bf16 [*,1024], B = W1T, out rows = assignments, N=F
    k_gemm<<<dim3(FF / BN, NTOK / BM, E_N), 256, 0, stream>>>(
        xb, W1T, b1, Hb, cnt, offs, assign_tok, DM, FF, DM);
    k_ln1<<<NA, 256, 0, stream>>>(Hb, g1, be1, assign_e);
    // GEMM2: A = h rows (already grouped by expert), B = W2T, N=D
    k_gemm<<<dim3(DM / BN, NTOK / BM, E_N), 256, 0, stream>>>(
        Hb, W2T, b2, Yb, cnt, offs, nullptr, FF, DM, FF);
    k_comb<<<NTOK, 256, 0, stream>>>(Yb, g2, be2, slot, topk_p, assign_e, out);
}

// Round 2
// 497.175 us; speedup vs baseline: 1.0804x; 1.0804x over previous
//
#include <hip/hip_runtime.h>

// Mixture-of-Experts, sparse top-2 implementation.
// Round 2: m97-style GEMM (global_load_lds width=16, swizzled LDS), better transpose.

#define E_N 8
#define TOPK 2
#define DM 1024
#define FF 4096
#define NTOK 4096           // B*S
#define NA 8192             // NTOK*TOPK assignments
#define LN_EPS 1e-5f

typedef __attribute__((ext_vector_type(4))) float f32x4;
typedef __attribute__((ext_vector_type(8))) short short8;

__device__ __forceinline__ unsigned short f2bf(float f) {
    unsigned int u = __builtin_bit_cast(unsigned int, f);
    u = (u + 0x7FFFu + ((u >> 16) & 1u)) >> 16;   // RNE
    return (unsigned short)u;
}
__device__ __forceinline__ float bf2f(unsigned short h) {
    unsigned int u = ((unsigned int)h) << 16;
    return __builtin_bit_cast(float, u);
}
__device__ __forceinline__ void unp(unsigned int u, float& lo, float& hi) {
    lo = bf2f((unsigned short)(u & 0xffffu));
    hi = bf2f((unsigned short)(u >> 16));
}
__device__ __forceinline__ unsigned int pk(float lo, float hi) {
    return (unsigned int)f2bf(lo) | ((unsigned int)f2bf(hi) << 16);
}

// async global->LDS, 16B per lane; lds base must be wave-uniform (HW adds lane*16)
__device__ __forceinline__ void gload16(const unsigned short* g, unsigned short* lds) {
    __builtin_amdgcn_global_load_lds(
        (const __attribute__((address_space(1))) unsigned int*)g,
        (__attribute__((address_space(3))) unsigned int*)lds, 16, 0, 0);
}

// ---------------- small utility kernels ----------------

__global__ void k_zero(int* p) { p[threadIdx.x] = 0; }

__global__ void k_conv_bf16(const float* __restrict__ src, unsigned short* __restrict__ dst, int n4) {
    int i = blockIdx.x * blockDim.x + threadIdx.x;
    if (i >= n4) return;
    float4 v = ((const float4*)src)[i];
    unsigned long long r =
        (unsigned long long)pk(v.x, v.y) | ((unsigned long long)pk(v.z, v.w) << 32);
    ((unsigned long long*)dst)[i] = r;
}

// [E][R][C] f32 -> [E][C][R] bf16, 64x64 tiles, packed 4B output stores
__global__ __launch_bounds__(256) void k_transpose_bf16(const float* __restrict__ src,
        unsigned short* __restrict__ dst, int R, int C) {
    __shared__ float tile[64][65];
    size_t e = blockIdx.z;
    const float* s = src + e * (size_t)R * C;
    unsigned short* d = dst + e * (size_t)R * C;
    int r0 = blockIdx.y * 64, c0 = blockIdx.x * 64;
    int tid = threadIdx.x;
    int lrow = tid >> 4, lcol = (tid & 15) * 4;
#pragma unroll
    for (int p = 0; p < 4; p++) {
        int r = lrow + p * 16;
        float4 v = *(const float4*)(s + (size_t)(r0 + r) * C + c0 + lcol);
        tile[r][lcol] = v.x; tile[r][lcol + 1] = v.y;
        tile[r][lcol + 2] = v.z; tile[r][lcol + 3] = v.w;
    }
    __syncthreads();
    int ocb = tid >> 5, rp = (tid & 31) * 2;
#pragma unroll
    for (int p = 0; p < 8; p++) {
        int oc = ocb + p * 8;
        unsigned int u = pk(tile[rp][oc], tile[rp + 1][oc]);
        *(unsigned int*)(d + (size_t)(c0 + oc) * R + r0 + rp) = u;
    }
}

// ---------------- router: logits -> softmax -> top2 -> renorm ----------------

__global__ __launch_bounds__(256) void k_router(const float* __restrict__ x,
        const float* __restrict__ Wr, const float* __restrict__ br,
        int* __restrict__ topk_idx, float* __restrict__ topk_p, int* __restrict__ cnt)
{
    int wv = threadIdx.x >> 6, lane = threadIdx.x & 63;
    int t = blockIdx.x * 4 + wv;
    const float* xr = x + (size_t)t * DM;
    float a0=0,a1=0,a2=0,a3=0,a4=0,a5=0,a6=0,a7=0;
    for (int d = lane; d < DM; d += 64) {
        float xv = xr[d];
        const float4* wp = (const float4*)(Wr + d * 8);
        float4 w0 = wp[0], w1 = wp[1];
        a0 += xv * w0.x; a1 += xv * w0.y; a2 += xv * w0.z; a3 += xv * w0.w;
        a4 += xv * w1.x; a5 += xv * w1.y; a6 += xv * w1.z; a7 += xv * w1.w;
    }
#pragma unroll
    for (int off = 32; off; off >>= 1) {
        a0 += __shfl_xor(a0, off); a1 += __shfl_xor(a1, off);
        a2 += __shfl_xor(a2, off); a3 += __shfl_xor(a3, off);
        a4 += __shfl_xor(a4, off); a5 += __shfl_xor(a5, off);
        a6 += __shfl_xor(a6, off); a7 += __shfl_xor(a7, off);
    }
    if (lane == 0) {
        float l[8] = {a0 + br[0], a1 + br[1], a2 + br[2], a3 + br[3],
                      a4 + br[4], a5 + br[5], a6 + br[6], a7 + br[7]};
        int i0 = 0;
#pragma unroll
        for (int e = 1; e < 8; e++) if (l[e] > l[i0]) i0 = e;
        int i1 = (i0 == 0) ? 1 : 0;
#pragma unroll
        for (int e = 0; e < 8; e++) if (e != i0 && l[e] > l[i1]) i1 = e;
        float p1 = expf(l[i1] - l[i0]);
        float s = 1.0f + p1;
        topk_idx[2 * t]     = i0;
        topk_idx[2 * t + 1] = i1;
        topk_p[2 * t]       = 1.0f / s;
        topk_p[2 * t + 1]   = p1 / s;
        atomicAdd(&cnt[i0], 1);
        atomicAdd(&cnt[i1], 1);
    }
}

__global__ void k_scan(const int* __restrict__ cnt, int* __restrict__ offs, int* __restrict__ fill) {
    if (threadIdx.x == 0) {
        int s = 0;
        for (int e = 0; e < E_N; e++) { offs[e] = s; fill[e] = s; s += cnt[e]; }
        offs[E_N] = s;
    }
}

__global__ void k_scatter(const int* __restrict__ topk_idx, int* __restrict__ fill,
                          int* __restrict__ assign_tok, int* __restrict__ assign_e,
                          int* __restrict__ slot) {
    int t = blockIdx.x * blockDim.x + threadIdx.x;
    if (t >= NTOK) return;
#pragma unroll
    for (int k = 0; k < TOPK; k++) {
        int e = topk_idx[2 * t + k];
        int pos = atomicAdd(&fill[e], 1);
        assign_tok[pos] = t;
        assign_e[pos] = e;
        slot[2 * t + k] = pos;
    }
}

// ---------------- grouped/gather GEMM (bf16 MFMA 16x16x32, m97 structure) ----
// C[off_e+m][n] = relu( sum_k A[row(m)][k] * BT[e][n][k] + bias[e][n] ), m < cnt[e]
// LDS tiles [128][64] bf16 linear, XOR-swizzled: phys_byte = log_byte ^ ((row&7)<<4).
// Staged via global_load_lds(16B): linear LDS dest, inverse-swizzled global source col.

#define BM 128
#define BN 128
#define BK 64

__global__ __launch_bounds__(256) void k_gemm(
    const unsigned short* __restrict__ A,
    const unsigned short* __restrict__ BT,
    const float* __restrict__ bias,
    unsigned short* __restrict__ C,
    const int* __restrict__ cnt, const int* __restrict__ offs,
    const int* __restrict__ gather_tok,
    int K, int N, int ldA)
{
    __shared__ __align__(1024) unsigned short A_lds[BM * BK];  // 16KB
    __shared__ __align__(1024) unsigned short B_lds[BN * BK];  // 16KB
    int e = blockIdx.z;
    int M = cnt[e];
    int m0 = blockIdx.y * BM;
    if (M <= 0 || m0 >= M) return;
    int n0 = blockIdx.x * BN;
    int off_e = offs[e];
    int tid = threadIdx.x;
    int wv = tid >> 6, lane = tid & 63;

    // staging: 16 x 1KB instructions per tile; wave wv covers j = wv*4 + i.
    // LDS phys byte o = j*1024 + lane*16 -> row = j*8 + (lane>>3), phys colblk = lane&7.
    // logical colblk = (lane&7) ^ (row&7) = (lane&7) ^ (lane>>3)   (inverse swizzle)
    int colsw = ((lane & 7) ^ (lane >> 3)) * 8;   // element offset within the BK window
    const unsigned short* aptr[4];
    const unsigned short* bptr[4];
    unsigned short* alds[4];
    unsigned short* blds[4];
#pragma unroll
    for (int i = 0; i < 4; i++) {
        int j = wv * 4 + i;
        int r = j * 8 + (lane >> 3);
        int ar = m0 + r; ar = (ar < M) ? ar : (M - 1);
        size_t arow = gather_tok ? (size_t)gather_tok[off_e + ar] : (size_t)(off_e + ar);
        aptr[i] = A + arow * (size_t)ldA + colsw;
        bptr[i] = BT + ((size_t)e * N + (n0 + r)) * (size_t)K + colsw;
        alds[i] = A_lds + j * 512;   // wave-uniform LDS base per instruction
        blds[i] = B_lds + j * 512;
    }

    int lr = lane & 15, hi = lane >> 4;
    int mW = (wv >> 1) * 64, nW = (wv & 1) * 64;

    f32x4 acc[4][4];
    f32x4 zz = {0.f, 0.f, 0.f, 0.f};
#pragma unroll
    for (int mi = 0; mi < 4; mi++)
#pragma unroll
        for (int ni = 0; ni < 4; ni++) acc[mi][ni] = zz;

    for (int k0 = 0; k0 < K; k0 += BK) {
        __syncthreads();                    // prev tile fully consumed
#pragma unroll
        for (int i = 0; i < 4; i++) {
            gload16(aptr[i] + k0, alds[i]);
            gload16(bptr[i] + k0, blds[i]);
        }
        __syncthreads();                    // compiler drains vmcnt before barrier
#pragma unroll
        for (int ks = 0; ks < 2; ks++) {
            // logical col byte = ks*64 + hi*16 ; phys = logical ^ ((row&7)<<4), row&7==lr&7
            int cb = (ks * 64 + hi * 16) ^ ((lr & 7) << 4);
            short8 af[4], bg[4];
#pragma unroll
            for (int mi = 0; mi < 4; mi++)
                af[mi] = *(const short8*)((const char*)A_lds + (mW + mi * 16 + lr) * 128 + cb);
#pragma unroll
            for (int ni = 0; ni < 4; ni++)
                bg[ni] = *(const short8*)((const char*)B_lds + (nW + ni * 16 + lr) * 128 + cb);
#pragma unroll
            for (int mi = 0; mi < 4; mi++)
#pragma unroll
                for (int ni = 0; ni < 4; ni++)
                    acc[mi][ni] = __builtin_amdgcn_mfma_f32_16x16x32_bf16(
                        af[mi], bg[ni], acc[mi][ni], 0, 0, 0);
        }
    }

    int lq = lane >> 4;
    float bv[4];
#pragma unroll
    for (int ni = 0; ni < 4; ni++)
        bv[ni] = bias[(size_t)e * N + (n0 + nW + ni * 16 + lr)];
#pragma unroll
    for (int mi = 0; mi < 4; mi++) {
        int mb = m0 + mW + mi * 16 + lq * 4;
#pragma unroll
        for (int r = 0; r < 4; r++) {
            int m = mb + r;
            if (m < M) {
                unsigned short* crow = C + (size_t)(off_e + m) * N;
#pragma unroll
                for (int ni = 0; ni < 4; ni++) {
                    float v = fmaxf(acc[mi][ni][r] + bv[ni], 0.0f);
                    crow[n0 + nW + ni * 16 + lr] = f2bf(v);
                }
            }
        }
    }
}

// ---------------- LN1 over F, in-place on h ----------------

__global__ __launch_bounds__(256) void k_ln1(unsigned short* __restrict__ H,
        const float* __restrict__ g, const float* __restrict__ b,
        const int* __restrict__ assign_e)
{
    size_t a = blockIdx.x;
    int e = assign_e[a];
    unsigned short* row = H + a * FF;
    int tid = threadIdx.x;
    uint4 u0 = *(const uint4*)(row + tid * 16);
    uint4 u1 = *(const uint4*)(row + tid * 16 + 8);
    float v[16];
    unp(u0.x, v[0], v[1]);  unp(u0.y, v[2], v[3]);
    unp(u0.z, v[4], v[5]);  unp(u0.w, v[6], v[7]);
    unp(u1.x, v[8], v[9]);  unp(u1.y, v[10], v[11]);
    unp(u1.z, v[12], v[13]); unp(u1.w, v[14], v[15]);
    float s = 0.f, q = 0.f;
#pragma unroll
    for (int i = 0; i < 16; i++) { s += v[i]; q += v[i] * v[i]; }
#pragma unroll
    for (int off = 32; off; off >>= 1) { s += __shfl_xor(s, off); q += __shfl_xor(q, off); }
    __shared__ float red[8];
    int wv = tid >> 6, lane = tid & 63;
    if (lane == 0) { red[wv * 2] = s; red[wv * 2 + 1] = q; }
    __syncthreads();
    s = red[0] + red[2] + red[4] + red[6];
    q = red[1] + red[3] + red[5] + red[7];
    float mu = s * (1.0f / FF);
    float var = q * (1.0f / FF) - mu * mu;
    float rstd = rsqrtf(var + LN_EPS);
    const float* gg = g + (size_t)e * FF + tid * 16;
    const float* bb = b + (size_t)e * FF + tid * 16;
    float4 G0 = *(const float4*)(gg);      float4 G1 = *(const float4*)(gg + 4);
    float4 G2 = *(const float4*)(gg + 8);  float4 G3 = *(const float4*)(gg + 12);
    float4 B0 = *(const float4*)(bb);      float4 B1 = *(const float4*)(bb + 4);
    float4 B2 = *(const float4*)(bb + 8);  float4 B3 = *(const float4*)(bb + 12);
    float gvv[16] = {G0.x,G0.y,G0.z,G0.w,G1.x,G1.y,G1.z,G1.w,G2.x,G2.y,G2.z,G2.w,G3.x,G3.y,G3.z,G3.w};
    float bvv[16] = {B0.x,B0.y,B0.z,B0.w,B1.x,B1.y,B1.z,B1.w,B2.x,B2.y,B2.z,B2.w,B3.x,B3.y,B3.z,B3.w};
#pragma unroll
    for (int i = 0; i < 16; i++) v[i] = (v[i] - mu) * rstd * gvv[i] + bvv[i];
    u0.x = pk(v[0], v[1]);  u0.y = pk(v[2], v[3]);
    u0.z = pk(v[4], v[5]);  u0.w = pk(v[6], v[7]);
    u1.x = pk(v[8], v[9]);  u1.y = pk(v[10], v[11]);
    u1.z = pk(v[12], v[13]); u1.w = pk(v[14], v[15]);
    *(uint4*)(row + tid * 16) = u0;
    *(uint4*)(row + tid * 16 + 8) = u1;
}

// ---------------- LN2 + gated combine ----------------

__global__ __launch_bounds__(256) void k_comb(const unsigned short* __restrict__ Y,
        const float* __restrict__ g, const float* __restrict__ b,
        const int* __restrict__ slot, const float* __restrict__ topk_p,
        const int* __restrict__ assign_e, float* __restrict__ out)
{
    int t = blockIdx.x;
    int s0 = slot[2 * t], s1 = slot[2 * t + 1];
    float p0 = topk_p[2 * t], p1 = topk_p[2 * t + 1];
    int e0 = assign_e[s0], e1 = assign_e[s1];
    int tid = threadIdx.x;
    uint2 ua = *(const uint2*)(Y + (size_t)s0 * DM + tid * 4);
    uint2 ub = *(const uint2*)(Y + (size_t)s1 * DM + tid * 4);
    float va[4], vb[4];
    unp(ua.x, va[0], va[1]); unp(ua.y, va[2], va[3]);
    unp(ub.x, vb[0], vb[1]); unp(ub.y, vb[2], vb[3]);
    float sa = 0.f, qa = 0.f, sb = 0.f, qb = 0.f;
#pragma unroll
    for (int i = 0; i < 4; i++) {
        sa += va[i]; qa += va[i] * va[i];
        sb += vb[i]; qb += vb[i] * vb[i];
    }
#pragma unroll
    for (int off = 32; off; off >>= 1) {
        sa += __shfl_xor(sa, off); qa += __shfl_xor(qa, off);
        sb += __shfl_xor(sb, off); qb += __shfl_xor(qb, off);
    }
    __shared__ float red[16];
    int wv = tid >> 6, lane = tid & 63;
    if (lane == 0) { red[wv*4+0]=sa; red[wv*4+1]=qa; red[wv*4+2]=sb; red[wv*4+3]=qb; }
    __syncthreads();
    sa = red[0] + red[4] + red[8]  + red[12];
    qa = red[1] + red[5] + red[9]  + red[13];
    sb = red[2] + red[6] + red[10] + red[14];
    qb = red[3] + red[7] + red[11] + red[15];
    float mua = sa * (1.0f / DM), vara = qa * (1.0f / DM) - mua * mua;
    float ra = rsqrtf(vara + LN_EPS);
    float mub = sb * (1.0f / DM), varb = qb * (1.0f / DM) - mub * mub;
    float rb = rsqrtf(varb + LN_EPS);
    int d = tid * 4;
    float4 ga  = *(const float4*)(g + (size_t)e0 * DM + d);
    float4 ba  = *(const float4*)(b + (size_t)e0 * DM + d);
    float4 gb4 = *(const float4*)(g + (size_t)e1 * DM + d);
    float4 bb4 = *(const float4*)(b + (size_t)e1 * DM + d);
    float4 o;
    o.x = p0 * ((va[0] - mua) * ra * ga.x + ba.x) + p1 * ((vb[0] - mub) * rb * gb4.x + bb4.x);
    o.y = p0 * ((va[1] - mua) * ra * ga.y + ba.y) + p1 * ((vb[1] - mub) * rb * gb4.y + bb4.y);
    o.z = p0 * ((va[2] - mua) * ra * ga.z + ba.z) + p1 * ((vb[2] - mub) * rb * gb4.z + bb4.z);
    o.w = p0 * ((va[3] - mua) * ra * ga.w + ba.w) + p1 * ((vb[3] - mub) * rb * gb4.w + bb4.w);
    *(float4*)(out + (size_t)t * DM + d) = o;
}

// ---------------- launch ----------------

extern "C" void kernel_launch(void* const* d_in, const int* in_sizes, int n_in,
                              void* d_out, int out_size, void* d_ws, size_t ws_size,
                              hipStream_t stream) {
    const float* x   = (const float*)d_in[0];
    const float* Wr  = (const float*)d_in[1];
    const float* br  = (const float*)d_in[2];
    const float* W1  = (const float*)d_in[3];
    const float* b1  = (const float*)d_in[4];
    const float* g1  = (const float*)d_in[5];
    const float* be1 = (const float*)d_in[6];
    const float* W2  = (const float*)d_in[7];
    const float* b2  = (const float*)d_in[8];
    const float* g2  = (const float*)d_in[9];
    const float* be2 = (const float*)d_in[10];
    float* out = (float*)d_out;

    char* w = (char*)d_ws;
    int*   cnt        = (int*)(w);
    int*   fill       = (int*)(w + 64);
    int*   offs       = (int*)(w + 128);
    int*   topk_idx   = (int*)(w + 512);
    float* topk_p     = (float*)(w + 512 + (32 << 10));
    int*   assign_tok = (int*)(w + 512 + (64 << 10));
    int*   assign_e   = (int*)(w + 512 + (96 << 10));
    int*   slot       = (int*)(w + 512 + (128 << 10));
    unsigned short* xb  = (unsigned short*)(w + ((size_t)1 << 20));
    unsigned short* W1T = (unsigned short*)(w + ((size_t)9 << 20));    // [E][F][D] bf16
    unsigned short* W2T = (unsigned short*)(w + ((size_t)73 << 20));   // [E][D][F] bf16
    unsigned short* Hb  = (unsigned short*)(w + ((size_t)137 << 20));  // [NA][F] bf16
    unsigned short* Yb  = (unsigned short*)(w + ((size_t)201 << 20));  // [NA][D] bf16

    k_zero<<<1, 64, 0, stream>>>((int*)w);
    k_conv_bf16<<<(NTOK * DM / 4 + 255) / 256, 256, 0, stream>>>(x, xb, NTOK * DM / 4);
    k_transpose_bf16<<<dim3(FF / 64, DM / 64, E_N), 256, 0, stream>>>(W1, W1T, DM, FF);
    k_transpose_bf16<<<dim3(DM / 64, FF / 64, E_N), 256, 0, stream>>>(W2, W2T, FF, DM);
    k_router<<<NTOK / 4, 256, 0, stream>>>(x, Wr, br, topk_idx, topk_p, cnt);
    k_scan<<<1, 64, 0, stream>>>(cnt, offs, fill);
    k_scatter<<<NTOK / 256, 256, 0, stream>>>(topk_idx, fill, assign_tok, assign_e, slot);
    k_gemm<<<dim3(FF / BN, NTOK / BM, E_N), 256, 0, stream>>>(
        xb, W1T, b1, Hb, cnt, offs, assign_tok, DM, FF, DM);
    k_ln1<<<NA, 256, 0, stream>>>(Hb, g1, be1, assign_e);
    k_gemm<<<dim3(DM / BN, NTOK / BM, E_N), 256, 0, stream>>>(
        Hb, W2T, b2, Yb, cnt, offs, nullptr, FF, DM, FF);
    k_comb<<<NTOK, 256, 0, stream>>>(Yb, g2, be2, slot, topk_p, assign_e, out);
}